// Round 6
// baseline (407.826 us; speedup 1.0000x reference)
//
#include <hip/hip_runtime.h>
#include <hip/hip_fp16.h>
#include <math.h>

#define N_NODES 50000
#define N_EDGES 400000
#define NUM_GRAPHS 64

// ---------------------------------------------------------------------------
// Factorized NNConv, fp16 tables, COLUMN-MAJOR-PER-NODE layout, SRC-SORTED edges:
//   msg[e,o] = sum_j relu(a_e*w1_j+b1_j) * P[src,j,o] + Q[src,o]
// P1: per node, 16 cols x 12 half items {P[j=0..9][o], Q[o], pad}  (384 B/row)
// P2: per node, 32 cols x 12 half items                             (768 B/row)
// Root terms stored dense fp32 (R1[N][16], R2[N][32]).
// Edges counting-sorted by src (hist -> single-block scan -> scatter); the
// sorted order gives L1/L2 row reuse in both edge kernels (table streamed ~1x
// instead of ~3.8x). dst in-degree (cntd) computed in the same histogram pass.
// ---------------------------------------------------------------------------

__global__ __launch_bounds__(256) void k0_hist(const int* __restrict__ src,
        const int* __restrict__ dst, int* __restrict__ deg, int* __restrict__ cntd) {
    int e = blockIdx.x * 256 + threadIdx.x;
    if (e < N_EDGES) {
        atomicAdd(deg + src[e], 1);
        atomicAdd(cntd + dst[e], 1);
    }
}

// single-block exclusive scan of deg[50000] -> woff (Hillis-Steele over 1024 partials)
__global__ __launch_bounds__(1024) void k0_scan(const int* __restrict__ deg,
        int* __restrict__ woff) {
    __shared__ int part[1024];
    int t = threadIdx.x;
    const int C = (N_NODES + 1023) / 1024;   // 49
    int base = t * C;
    int s = 0;
    for (int i = 0; i < C; i++) {
        int n = base + i;
        if (n < N_NODES) s += deg[n];
    }
    part[t] = s;
    __syncthreads();
    for (int off = 1; off < 1024; off <<= 1) {
        int v = (t >= off) ? part[t - off] : 0;
        __syncthreads();
        part[t] += v;
        __syncthreads();
    }
    int run = (t == 0) ? 0 : part[t - 1];
    for (int i = 0; i < C; i++) {
        int n = base + i;
        if (n < N_NODES) { woff[n] = run; run += deg[n]; }
    }
}

__global__ __launch_bounds__(256) void k0_scatter(const int* __restrict__ src,
        const int* __restrict__ dst, const float* __restrict__ ea,
        int* __restrict__ woff, int* __restrict__ ses, int* __restrict__ sed,
        float* __restrict__ sea) {
    int e = blockIdx.x * 256 + threadIdx.x;
    if (e < N_EDGES) {
        int s = src[e];
        int pos = atomicAdd(woff + s, 1);
        ses[pos] = s;
        sed[pos] = dst[e];
        sea[pos] = ea[e];
    }
}

__global__ __launch_bounds__(256) void k1_p1(const float* __restrict__ x,
        const float* __restrict__ w2, const float* __restrict__ b2,
        const float* __restrict__ root, __half* __restrict__ P,
        float* __restrict__ R1) {
    __shared__ float Wl[32][192];   // [i][m*16+o]
    __shared__ float xl[16][32];
    int t = threadIdx.x;
    for (int idx = t; idx < 32 * 192; idx += 256) {
        int i = idx / 192, c = idx % 192;
        int m = c >> 4, o = c & 15;
        float w;
        if (m < 10)       w = w2[m * 512 + i * 16 + o];
        else if (m == 10) w = b2[i * 16 + o];
        else              w = root[i * 16 + o];
        Wl[i][c] = w;
    }
    int n0 = blockIdx.x * 16;
    for (int idx = t; idx < 16 * 32; idx += 256) {
        int nl = idx >> 5, i = idx & 31;
        int n = n0 + nl;
        xl[nl][i] = (n < N_NODES) ? x[n * 32 + i] : 0.f;
    }
    __syncthreads();
    int nl = t >> 4, o = t & 15;
    int n = n0 + nl;
    if (n >= N_NODES) return;
    float acc[12];
#pragma unroll
    for (int m = 0; m < 12; m++) acc[m] = 0.f;
#pragma unroll
    for (int i = 0; i < 32; i++) {
        float xv = xl[nl][i];
#pragma unroll
        for (int m = 0; m < 12; m++) acc[m] += xv * Wl[i][m * 16 + o];
    }
    __half2* Po = (__half2*)(P + (size_t)n * 192 + o * 12);
#pragma unroll
    for (int k = 0; k < 6; k++) Po[k] = __floats2half2_rn(acc[2 * k], acc[2 * k + 1]);
    R1[n * 16 + o] = acc[11];
}

// fused: h1 = elu(agg1/cnt + R1 + bias1) computed in prologue (never stored)
__global__ __launch_bounds__(256) void k4_p2(const float* __restrict__ agg1,
        const int* __restrict__ cntd, const float* __restrict__ R1,
        const float* __restrict__ bias1,
        const float* __restrict__ w2, const float* __restrict__ b2,
        const float* __restrict__ root, __half* __restrict__ P2,
        float* __restrict__ R2) {
    __shared__ float Wl[16][384];   // [i][m*32+o]
    __shared__ float hl[8][16];
    int t = threadIdx.x;
    for (int idx = t; idx < 16 * 384; idx += 256) {
        int i = idx / 384, c = idx % 384;
        int m = c >> 5, o = c & 31;
        float w;
        if (m < 10)       w = w2[m * 512 + i * 32 + o];
        else if (m == 10) w = b2[i * 32 + o];
        else              w = root[i * 32 + o];
        Wl[i][c] = w;
    }
    int n0 = blockIdx.x * 8;
    if (t < 128) {
        int nl = t >> 4, i = t & 15;
        int n = n0 + nl;
        float v = 0.f;
        if (n < N_NODES) {
            int ci = cntd[n];
            float c = (float)(ci > 0 ? ci : 1);
            v = agg1[n * 16 + i] / c + R1[n * 16 + i] + bias1[i];
            v = v > 0.f ? v : expm1f(v);
        }
        hl[nl][i] = v;
    }
    __syncthreads();
    int nl = t >> 5, o = t & 31;
    int n = n0 + nl;
    if (n >= N_NODES) return;
    float acc[12];
#pragma unroll
    for (int m = 0; m < 12; m++) acc[m] = 0.f;
#pragma unroll
    for (int i = 0; i < 16; i++) {
        float hv = hl[nl][i];
#pragma unroll
        for (int m = 0; m < 12; m++) acc[m] += hv * Wl[i][m * 32 + o];
    }
    __half2* Po = (__half2*)(P2 + (size_t)n * 384 + o * 12);
#pragma unroll
    for (int k = 0; k < 6; k++) Po[k] = __floats2half2_rn(acc[2 * k], acc[2 * k + 1]);
    R2[(size_t)n * 32 + o] = acc[11];
}

// conv1 edges (src-sorted): 16 lanes/edge, 3 independent float2 loads, 1 atomic/lane
__global__ __launch_bounds__(256) void k2_edge1(const __half* __restrict__ P,
        const int* __restrict__ ses, const int* __restrict__ sed,
        const float* __restrict__ sea, const float* __restrict__ w1,
        const float* __restrict__ b1, float* __restrict__ agg) {
    int t = threadIdx.x;
    int e = blockIdx.x * 16 + (t >> 4);
    int o = t & 15;
    if (e >= N_EDGES) return;
    float a = sea[e];
    int s = ses[e], d = sed[e];
    const float2* Pf = (const float2*)P;
    int base = s * 48 + o * 3;
    float2 f0 = Pf[base];
    float2 f1 = Pf[base + 1];
    float2 f2 = Pf[base + 2];
    float r[10];
#pragma unroll
    for (int j = 0; j < 10; j++) r[j] = fmaxf(a * w1[j] + b1[j], 0.f);
    union { float2 f; __half2 h[2]; } u;
    float m;
    {
        u.f = f2;                       // items (8,9) (Q,pad)
        float2 p89 = __half22float2(u.h[0]);
        float2 pQR = __half22float2(u.h[1]);
        m = pQR.x + r[8] * p89.x + r[9] * p89.y;
    }
    {
        u.f = f0;
        float2 p01 = __half22float2(u.h[0]);
        float2 p23 = __half22float2(u.h[1]);
        m += r[0] * p01.x + r[1] * p01.y + r[2] * p23.x + r[3] * p23.y;
    }
    {
        u.f = f1;
        float2 p45 = __half22float2(u.h[0]);
        float2 p67 = __half22float2(u.h[1]);
        m += r[4] * p45.x + r[5] * p45.y + r[6] * p67.x + r[7] * p67.y;
    }
    atomicAdd(agg + d * 16 + o, m);
}

// conv2 edges (src-sorted): 32 lanes/edge
__global__ __launch_bounds__(256) void k5_edge2(const __half* __restrict__ P,
        const int* __restrict__ ses, const int* __restrict__ sed,
        const float* __restrict__ sea, const float* __restrict__ w1,
        const float* __restrict__ b1, float* __restrict__ agg) {
    int t = threadIdx.x;
    int e = blockIdx.x * 8 + (t >> 5);
    int o = t & 31;
    if (e >= N_EDGES) return;
    float a = sea[e];
    int s = ses[e], d = sed[e];
    const float2* Pf = (const float2*)P;
    int base = s * 96 + o * 3;
    float2 f0 = Pf[base];
    float2 f1 = Pf[base + 1];
    float2 f2 = Pf[base + 2];
    float r[10];
#pragma unroll
    for (int j = 0; j < 10; j++) r[j] = fmaxf(a * w1[j] + b1[j], 0.f);
    union { float2 f; __half2 h[2]; } u;
    float m;
    {
        u.f = f2;
        float2 p89 = __half22float2(u.h[0]);
        float2 pQR = __half22float2(u.h[1]);
        m = pQR.x + r[8] * p89.x + r[9] * p89.y;
    }
    {
        u.f = f0;
        float2 p01 = __half22float2(u.h[0]);
        float2 p23 = __half22float2(u.h[1]);
        m += r[0] * p01.x + r[1] * p01.y + r[2] * p23.x + r[3] * p23.y;
    }
    {
        u.f = f1;
        float2 p45 = __half22float2(u.h[0]);
        float2 p67 = __half22float2(u.h[1]);
        m += r[4] * p45.x + r[5] * p45.y + r[6] * p67.x + r[7] * p67.y;
    }
    atomicAdd(agg + d * 32 + o, m);
}

// High-occupancy pooling partials: 512 blocks, 8 node-lanes x 32 cols.
__global__ __launch_bounds__(256) void k6_partial(const float* __restrict__ agg2,
        const int* __restrict__ cntd, const float* __restrict__ R2,
        const float* __restrict__ bias2, const int* __restrict__ batch,
        float* __restrict__ gsum) {
    const int NB = 512;
    const int chunk = (N_NODES + NB - 1) / NB;   // 98
    int begin = blockIdx.x * chunk;
    int end = begin + chunk;
    if (end > N_NODES) end = N_NODES;
    int t = threadIdx.x;
    int o = t & 31, ch = t >> 5;
    float bz = bias2[o];
    float acc = 0.f;
    int cur_g = -1;
    for (int n = begin + ch; n < end; n += 8) {
        int g = batch[n];
        int ci = cntd[n];
        float c = (float)(ci > 0 ? ci : 1);
        float v = agg2[(size_t)n * 32 + o] / c + R2[(size_t)n * 32 + o] + bz;
        v = v > 0.f ? v : expm1f(v);
        if (g != cur_g) {
            if (cur_g >= 0) atomicAdd(gsum + cur_g * 32 + o, acc);
            cur_g = g; acc = 0.f;
        }
        acc += v;
    }
    if (cur_g >= 0) atomicAdd(gsum + cur_g * 32 + o, acc);
}

// head: mean finalize (counts via binary search on sorted batch) + fc1 + fc2 + log_softmax
__global__ __launch_bounds__(256) void k8_head(const float* __restrict__ gsum,
        const int* __restrict__ batch,
        const float* __restrict__ fc1w, const float* __restrict__ fc1b,
        const float* __restrict__ fc2w, const float* __restrict__ fc2b,
        float* __restrict__ out) {
    __shared__ float gl[64][32];
    __shared__ float w1l[32][64];
    __shared__ float hl[64][64];
    __shared__ float zl[64][2];
    __shared__ float gc[64];
    int t = threadIdx.x;
    if (t < 64) {
        int g = t;
        int lo = 0, hi = N_NODES;
        while (lo < hi) { int mid = (lo + hi) >> 1; if (batch[mid] < g) lo = mid + 1; else hi = mid; }
        int s0 = lo;
        lo = 0; hi = N_NODES;
        while (lo < hi) { int mid = (lo + hi) >> 1; if (batch[mid] < g + 1) lo = mid + 1; else hi = mid; }
        gc[g] = fmaxf((float)(lo - s0), 1.0f);
    }
    for (int idx = t; idx < 32 * 64; idx += 256) w1l[idx >> 6][idx & 63] = fc1w[idx];
    __syncthreads();
    for (int idx = t; idx < 64 * 32; idx += 256) gl[idx >> 5][idx & 31] = gsum[idx] / gc[idx >> 5];
    __syncthreads();
    for (int idx = t; idx < 64 * 64; idx += 256) {
        int gg = idx >> 6, c = idx & 63;
        float acc = fc1b[c];
#pragma unroll
        for (int i = 0; i < 32; i++) acc += gl[gg][i] * w1l[i][c];
        hl[gg][c] = acc > 0.f ? acc : expm1f(acc);
    }
    __syncthreads();
    if (t < 128) {
        int gg = t >> 1, k = t & 1;
        float acc = fc2b[k];
#pragma unroll
        for (int c = 0; c < 64; c++) acc += hl[gg][c] * fc2w[c * 2 + k];
        zl[gg][k] = acc;
    }
    __syncthreads();
    if (t < 128) {
        int gg = t >> 1, k = t & 1;
        float z0 = zl[gg][0], z1 = zl[gg][1];
        float m = fmaxf(z0, z1);
        float lse = m + logf(expf(z0 - m) + expf(z1 - m));
        out[t] = zl[gg][k] - lse;
    }
}

extern "C" void kernel_launch(void* const* d_in, const int* in_sizes, int n_in,
                              void* d_out, int out_size, void* d_ws, size_t ws_size,
                              hipStream_t stream) {
    const float* x       = (const float*)d_in[0];
    const int*   ei      = (const int*)d_in[1];
    const float* ea      = (const float*)d_in[2];
    const int*   batch   = (const int*)d_in[3];
    const float* nn1_w1  = (const float*)d_in[4];
    const float* nn1_b1  = (const float*)d_in[5];
    const float* nn1_w2  = (const float*)d_in[6];
    const float* nn1_b2  = (const float*)d_in[7];
    const float* c1_root = (const float*)d_in[8];
    const float* c1_bias = (const float*)d_in[9];
    const float* nn2_w1  = (const float*)d_in[10];
    const float* nn2_b1  = (const float*)d_in[11];
    const float* nn2_w2  = (const float*)d_in[12];
    const float* nn2_b2  = (const float*)d_in[13];
    const float* c2_root = (const float*)d_in[14];
    const float* c2_bias = (const float*)d_in[15];
    const float* fc1w    = (const float*)d_in[16];
    const float* fc1b    = (const float*)d_in[17];
    const float* fc2w    = (const float*)d_in[18];
    const float* fc2b    = (const float*)d_in[19];
    const int* src = ei;
    const int* dst = ei + N_EDGES;

    char* ws = (char*)d_ws;
    size_t off = 0;
    __half* P1 = (__half*)(ws + off); off += (size_t)N_NODES * 192 * 2;  // 19.2 MB
    __half* P2 = (__half*)(ws + off); off += (size_t)N_NODES * 384 * 2;  // 38.4 MB
    float* R1  = (float*)(ws + off);  off += (size_t)N_NODES * 16 * 4;
    float* R2  = (float*)(ws + off);  off += (size_t)N_NODES * 32 * 4;
    // ---- zeroed region (contiguous, one memset) ----
    char* zbase = ws + off;
    int*   deg  = (int*)(ws + off);   off += (size_t)N_NODES * 4;
    int*   cntd = (int*)(ws + off);   off += (size_t)N_NODES * 4;
    float* agg1 = (float*)(ws + off); off += (size_t)N_NODES * 16 * 4;
    float* agg2 = (float*)(ws + off); off += (size_t)N_NODES * 32 * 4;
    float* gsum = (float*)(ws + off); off += (size_t)NUM_GRAPHS * 32 * 4;
    size_t zbytes = (size_t)(ws + off - zbase);
    // ---- sort buffers (fully overwritten each call) ----
    int*   woff = (int*)(ws + off);   off += (size_t)N_NODES * 4;
    int*   ses  = (int*)(ws + off);   off += (size_t)N_EDGES * 4;
    int*   sed  = (int*)(ws + off);   off += (size_t)N_EDGES * 4;
    float* sea  = (float*)(ws + off); off += (size_t)N_EDGES * 4;

    hipMemsetAsync(zbase, 0, zbytes, stream);

    k0_hist<<<(N_EDGES + 255) / 256, 256, 0, stream>>>(src, dst, deg, cntd);
    k0_scan<<<1, 1024, 0, stream>>>(deg, woff);
    k0_scatter<<<(N_EDGES + 255) / 256, 256, 0, stream>>>(src, dst, ea, woff, ses, sed, sea);
    k1_p1<<<(N_NODES + 15) / 16, 256, 0, stream>>>(x, nn1_w2, nn1_b2, c1_root, P1, R1);
    k2_edge1<<<(N_EDGES + 15) / 16, 256, 0, stream>>>(P1, ses, sed, sea, nn1_w1, nn1_b1, agg1);
    k4_p2<<<(N_NODES + 7) / 8, 256, 0, stream>>>(agg1, cntd, R1, c1_bias, nn2_w2, nn2_b2, c2_root, P2, R2);
    k5_edge2<<<(N_EDGES + 7) / 8, 256, 0, stream>>>(P2, ses, sed, sea, nn2_w1, nn2_b1, agg2);
    k6_partial<<<512, 256, 0, stream>>>(agg2, cntd, R2, c2_bias, batch, gsum);
    k8_head<<<1, 256, 0, stream>>>(gsum, batch, fc1w, fc1b, fc2w, fc2b, (float*)d_out);
}

// Round 7
// 321.348 us; speedup vs baseline: 1.2691x; 1.2691x over previous
//
#include <hip/hip_runtime.h>
#include <hip/hip_fp16.h>
#include <math.h>

#define N_NODES 50000
#define N_EDGES 400000
#define NUM_GRAPHS 64
#define NSCAN_BLK ((N_NODES + 1023) / 1024)   // 49

// ---------------------------------------------------------------------------
// Factorized NNConv, fp16 tables, COLUMN-MAJOR-PER-NODE layout, SRC-SORTED edges:
//   msg[e,o] = sum_j relu(a_e*w1_j+b1_j) * P[src,j,o] + Q[src,o]
// P1: per node, 16 cols x 12 half items {P[j=0..9][o], Q[o], pad}  (384 B/row)
// P2: per node, 32 cols x 12 half items                             (768 B/row)
// Root terms stored dense fp32 (R1[N][16], R2[N][32]).
// Edges counting-sorted by src (hist -> hierarchical scan -> scatter); sorted
// order gives L1/L2 row reuse in both edge kernels. dst in-degree (cntd)
// computed in the same histogram pass.
// ---------------------------------------------------------------------------

__global__ __launch_bounds__(256) void k0_hist(const int* __restrict__ src,
        const int* __restrict__ dst, int* __restrict__ deg, int* __restrict__ cntd) {
    int e = blockIdx.x * 256 + threadIdx.x;
    if (e < N_EDGES) {
        atomicAdd(deg + src[e], 1);
        atomicAdd(cntd + dst[e], 1);
    }
}

// hierarchical scan, stage A: per-block 1024-element in-LDS scan + block totals
__global__ __launch_bounds__(1024) void k0_scanA(const int* __restrict__ deg,
        int* __restrict__ woff, int* __restrict__ bsum) {
    __shared__ int tmp[1024];
    int b = blockIdx.x, t = threadIdx.x;
    int n = b * 1024 + t;
    int v = (n < N_NODES) ? deg[n] : 0;
    tmp[t] = v;
    __syncthreads();
    for (int off = 1; off < 1024; off <<= 1) {
        int add = (t >= off) ? tmp[t - off] : 0;
        __syncthreads();
        tmp[t] += add;
        __syncthreads();
    }
    if (n < N_NODES) woff[n] = tmp[t] - v;   // exclusive within block
    if (t == 1023) bsum[b] = tmp[1023];
}

// stage B: add prefix of block totals (<=49 values, thread-0 sums, broadcast)
__global__ __launch_bounds__(1024) void k0_scanB(const int* __restrict__ bsum,
        int* __restrict__ woff) {
    __shared__ int boff;
    int b = blockIdx.x, t = threadIdx.x;
    if (t == 0) {
        int s = 0;
        for (int i = 0; i < b; i++) s += bsum[i];
        boff = s;
    }
    __syncthreads();
    int n = b * 1024 + t;
    if (n < N_NODES) woff[n] += boff;
}

__global__ __launch_bounds__(256) void k0_scatter(const int* __restrict__ src,
        const int* __restrict__ dst, const float* __restrict__ ea,
        int* __restrict__ woff, int* __restrict__ ses, int* __restrict__ sed,
        float* __restrict__ sea) {
    int e = blockIdx.x * 256 + threadIdx.x;
    if (e < N_EDGES) {
        int s = src[e];
        int pos = atomicAdd(woff + s, 1);
        ses[pos] = s;
        sed[pos] = dst[e];
        sea[pos] = ea[e];
    }
}

__global__ __launch_bounds__(256) void k1_p1(const float* __restrict__ x,
        const float* __restrict__ w2, const float* __restrict__ b2,
        const float* __restrict__ root, __half* __restrict__ P,
        float* __restrict__ R1) {
    __shared__ float Wl[32][192];   // [i][m*16+o]
    __shared__ float xl[16][32];
    int t = threadIdx.x;
    for (int idx = t; idx < 32 * 192; idx += 256) {
        int i = idx / 192, c = idx % 192;
        int m = c >> 4, o = c & 15;
        float w;
        if (m < 10)       w = w2[m * 512 + i * 16 + o];
        else if (m == 10) w = b2[i * 16 + o];
        else              w = root[i * 16 + o];
        Wl[i][c] = w;
    }
    int n0 = blockIdx.x * 16;
    for (int idx = t; idx < 16 * 32; idx += 256) {
        int nl = idx >> 5, i = idx & 31;
        int n = n0 + nl;
        xl[nl][i] = (n < N_NODES) ? x[n * 32 + i] : 0.f;
    }
    __syncthreads();
    int nl = t >> 4, o = t & 15;
    int n = n0 + nl;
    if (n >= N_NODES) return;
    float acc[12];
#pragma unroll
    for (int m = 0; m < 12; m++) acc[m] = 0.f;
#pragma unroll
    for (int i = 0; i < 32; i++) {
        float xv = xl[nl][i];
#pragma unroll
        for (int m = 0; m < 12; m++) acc[m] += xv * Wl[i][m * 16 + o];
    }
    __half2* Po = (__half2*)(P + (size_t)n * 192 + o * 12);
#pragma unroll
    for (int k = 0; k < 6; k++) Po[k] = __floats2half2_rn(acc[2 * k], acc[2 * k + 1]);
    R1[n * 16 + o] = acc[11];
}

// fused: h1 = elu(agg1/cnt + R1 + bias1) computed in prologue (never stored)
__global__ __launch_bounds__(256) void k4_p2(const float* __restrict__ agg1,
        const int* __restrict__ cntd, const float* __restrict__ R1,
        const float* __restrict__ bias1,
        const float* __restrict__ w2, const float* __restrict__ b2,
        const float* __restrict__ root, __half* __restrict__ P2,
        float* __restrict__ R2) {
    __shared__ float Wl[16][384];   // [i][m*32+o]
    __shared__ float hl[8][16];
    int t = threadIdx.x;
    for (int idx = t; idx < 16 * 384; idx += 256) {
        int i = idx / 384, c = idx % 384;
        int m = c >> 5, o = c & 31;
        float w;
        if (m < 10)       w = w2[m * 512 + i * 32 + o];
        else if (m == 10) w = b2[i * 32 + o];
        else              w = root[i * 32 + o];
        Wl[i][c] = w;
    }
    int n0 = blockIdx.x * 8;
    if (t < 128) {
        int nl = t >> 4, i = t & 15;
        int n = n0 + nl;
        float v = 0.f;
        if (n < N_NODES) {
            int ci = cntd[n];
            float c = (float)(ci > 0 ? ci : 1);
            v = agg1[n * 16 + i] / c + R1[n * 16 + i] + bias1[i];
            v = v > 0.f ? v : expm1f(v);
        }
        hl[nl][i] = v;
    }
    __syncthreads();
    int nl = t >> 5, o = t & 31;
    int n = n0 + nl;
    if (n >= N_NODES) return;
    float acc[12];
#pragma unroll
    for (int m = 0; m < 12; m++) acc[m] = 0.f;
#pragma unroll
    for (int i = 0; i < 16; i++) {
        float hv = hl[nl][i];
#pragma unroll
        for (int m = 0; m < 12; m++) acc[m] += hv * Wl[i][m * 32 + o];
    }
    __half2* Po = (__half2*)(P2 + (size_t)n * 384 + o * 12);
#pragma unroll
    for (int k = 0; k < 6; k++) Po[k] = __floats2half2_rn(acc[2 * k], acc[2 * k + 1]);
    R2[(size_t)n * 32 + o] = acc[11];
}

// conv1 edges (src-sorted): 16 lanes/edge, 3 independent float2 loads, 1 atomic/lane
__global__ __launch_bounds__(256) void k2_edge1(const __half* __restrict__ P,
        const int* __restrict__ ses, const int* __restrict__ sed,
        const float* __restrict__ sea, const float* __restrict__ w1,
        const float* __restrict__ b1, float* __restrict__ agg) {
    int t = threadIdx.x;
    int e = blockIdx.x * 16 + (t >> 4);
    int o = t & 15;
    if (e >= N_EDGES) return;
    float a = sea[e];
    int s = ses[e], d = sed[e];
    const float2* Pf = (const float2*)P;
    int base = s * 48 + o * 3;
    float2 f0 = Pf[base];
    float2 f1 = Pf[base + 1];
    float2 f2 = Pf[base + 2];
    float r[10];
#pragma unroll
    for (int j = 0; j < 10; j++) r[j] = fmaxf(a * w1[j] + b1[j], 0.f);
    union { float2 f; __half2 h[2]; } u;
    float m;
    {
        u.f = f2;                       // items (8,9) (Q,pad)
        float2 p89 = __half22float2(u.h[0]);
        float2 pQR = __half22float2(u.h[1]);
        m = pQR.x + r[8] * p89.x + r[9] * p89.y;
    }
    {
        u.f = f0;
        float2 p01 = __half22float2(u.h[0]);
        float2 p23 = __half22float2(u.h[1]);
        m += r[0] * p01.x + r[1] * p01.y + r[2] * p23.x + r[3] * p23.y;
    }
    {
        u.f = f1;
        float2 p45 = __half22float2(u.h[0]);
        float2 p67 = __half22float2(u.h[1]);
        m += r[4] * p45.x + r[5] * p45.y + r[6] * p67.x + r[7] * p67.y;
    }
    atomicAdd(agg + d * 16 + o, m);
}

// conv2 edges (src-sorted): 32 lanes/edge
__global__ __launch_bounds__(256) void k5_edge2(const __half* __restrict__ P,
        const int* __restrict__ ses, const int* __restrict__ sed,
        const float* __restrict__ sea, const float* __restrict__ w1,
        const float* __restrict__ b1, float* __restrict__ agg) {
    int t = threadIdx.x;
    int e = blockIdx.x * 8 + (t >> 5);
    int o = t & 31;
    if (e >= N_EDGES) return;
    float a = sea[e];
    int s = ses[e], d = sed[e];
    const float2* Pf = (const float2*)P;
    int base = s * 96 + o * 3;
    float2 f0 = Pf[base];
    float2 f1 = Pf[base + 1];
    float2 f2 = Pf[base + 2];
    float r[10];
#pragma unroll
    for (int j = 0; j < 10; j++) r[j] = fmaxf(a * w1[j] + b1[j], 0.f);
    union { float2 f; __half2 h[2]; } u;
    float m;
    {
        u.f = f2;
        float2 p89 = __half22float2(u.h[0]);
        float2 pQR = __half22float2(u.h[1]);
        m = pQR.x + r[8] * p89.x + r[9] * p89.y;
    }
    {
        u.f = f0;
        float2 p01 = __half22float2(u.h[0]);
        float2 p23 = __half22float2(u.h[1]);
        m += r[0] * p01.x + r[1] * p01.y + r[2] * p23.x + r[3] * p23.y;
    }
    {
        u.f = f1;
        float2 p45 = __half22float2(u.h[0]);
        float2 p67 = __half22float2(u.h[1]);
        m += r[4] * p45.x + r[5] * p45.y + r[6] * p67.x + r[7] * p67.y;
    }
    atomicAdd(agg + d * 32 + o, m);
}

// High-occupancy pooling partials: 512 blocks, 8 node-lanes x 32 cols.
__global__ __launch_bounds__(256) void k6_partial(const float* __restrict__ agg2,
        const int* __restrict__ cntd, const float* __restrict__ R2,
        const float* __restrict__ bias2, const int* __restrict__ batch,
        float* __restrict__ gsum) {
    const int NB = 512;
    const int chunk = (N_NODES + NB - 1) / NB;   // 98
    int begin = blockIdx.x * chunk;
    int end = begin + chunk;
    if (end > N_NODES) end = N_NODES;
    int t = threadIdx.x;
    int o = t & 31, ch = t >> 5;
    float bz = bias2[o];
    float acc = 0.f;
    int cur_g = -1;
    for (int n = begin + ch; n < end; n += 8) {
        int g = batch[n];
        int ci = cntd[n];
        float c = (float)(ci > 0 ? ci : 1);
        float v = agg2[(size_t)n * 32 + o] / c + R2[(size_t)n * 32 + o] + bz;
        v = v > 0.f ? v : expm1f(v);
        if (g != cur_g) {
            if (cur_g >= 0) atomicAdd(gsum + cur_g * 32 + o, acc);
            cur_g = g; acc = 0.f;
        }
        acc += v;
    }
    if (cur_g >= 0) atomicAdd(gsum + cur_g * 32 + o, acc);
}

// head: mean finalize (counts via binary search on sorted batch) + fc1 + fc2 + log_softmax
__global__ __launch_bounds__(256) void k8_head(const float* __restrict__ gsum,
        const int* __restrict__ batch,
        const float* __restrict__ fc1w, const float* __restrict__ fc1b,
        const float* __restrict__ fc2w, const float* __restrict__ fc2b,
        float* __restrict__ out) {
    __shared__ float gl[64][32];
    __shared__ float w1l[32][64];
    __shared__ float hl[64][64];
    __shared__ float zl[64][2];
    __shared__ float gc[64];
    int t = threadIdx.x;
    if (t < 64) {
        int g = t;
        int lo = 0, hi = N_NODES;
        while (lo < hi) { int mid = (lo + hi) >> 1; if (batch[mid] < g) lo = mid + 1; else hi = mid; }
        int s0 = lo;
        lo = 0; hi = N_NODES;
        while (lo < hi) { int mid = (lo + hi) >> 1; if (batch[mid] < g + 1) lo = mid + 1; else hi = mid; }
        gc[g] = fmaxf((float)(lo - s0), 1.0f);
    }
    for (int idx = t; idx < 32 * 64; idx += 256) w1l[idx >> 6][idx & 63] = fc1w[idx];
    __syncthreads();
    for (int idx = t; idx < 64 * 32; idx += 256) gl[idx >> 5][idx & 31] = gsum[idx] / gc[idx >> 5];
    __syncthreads();
    for (int idx = t; idx < 64 * 64; idx += 256) {
        int gg = idx >> 6, c = idx & 63;
        float acc = fc1b[c];
#pragma unroll
        for (int i = 0; i < 32; i++) acc += gl[gg][i] * w1l[i][c];
        hl[gg][c] = acc > 0.f ? acc : expm1f(acc);
    }
    __syncthreads();
    if (t < 128) {
        int gg = t >> 1, k = t & 1;
        float acc = fc2b[k];
#pragma unroll
        for (int c = 0; c < 64; c++) acc += hl[gg][c] * fc2w[c * 2 + k];
        zl[gg][k] = acc;
    }
    __syncthreads();
    if (t < 128) {
        int gg = t >> 1, k = t & 1;
        float z0 = zl[gg][0], z1 = zl[gg][1];
        float m = fmaxf(z0, z1);
        float lse = m + logf(expf(z0 - m) + expf(z1 - m));
        out[t] = zl[gg][k] - lse;
    }
}

extern "C" void kernel_launch(void* const* d_in, const int* in_sizes, int n_in,
                              void* d_out, int out_size, void* d_ws, size_t ws_size,
                              hipStream_t stream) {
    const float* x       = (const float*)d_in[0];
    const int*   ei      = (const int*)d_in[1];
    const float* ea      = (const float*)d_in[2];
    const int*   batch   = (const int*)d_in[3];
    const float* nn1_w1  = (const float*)d_in[4];
    const float* nn1_b1  = (const float*)d_in[5];
    const float* nn1_w2  = (const float*)d_in[6];
    const float* nn1_b2  = (const float*)d_in[7];
    const float* c1_root = (const float*)d_in[8];
    const float* c1_bias = (const float*)d_in[9];
    const float* nn2_w1  = (const float*)d_in[10];
    const float* nn2_b1  = (const float*)d_in[11];
    const float* nn2_w2  = (const float*)d_in[12];
    const float* nn2_b2  = (const float*)d_in[13];
    const float* c2_root = (const float*)d_in[14];
    const float* c2_bias = (const float*)d_in[15];
    const float* fc1w    = (const float*)d_in[16];
    const float* fc1b    = (const float*)d_in[17];
    const float* fc2w    = (const float*)d_in[18];
    const float* fc2b    = (const float*)d_in[19];
    const int* src = ei;
    const int* dst = ei + N_EDGES;

    char* ws = (char*)d_ws;
    size_t off = 0;
    __half* P1 = (__half*)(ws + off); off += (size_t)N_NODES * 192 * 2;  // 19.2 MB
    __half* P2 = (__half*)(ws + off); off += (size_t)N_NODES * 384 * 2;  // 38.4 MB
    float* R1  = (float*)(ws + off);  off += (size_t)N_NODES * 16 * 4;
    float* R2  = (float*)(ws + off);  off += (size_t)N_NODES * 32 * 4;
    // ---- zeroed region (contiguous, one memset) ----
    char* zbase = ws + off;
    int*   deg  = (int*)(ws + off);   off += (size_t)N_NODES * 4;
    int*   cntd = (int*)(ws + off);   off += (size_t)N_NODES * 4;
    float* agg1 = (float*)(ws + off); off += (size_t)N_NODES * 16 * 4;
    float* agg2 = (float*)(ws + off); off += (size_t)N_NODES * 32 * 4;
    float* gsum = (float*)(ws + off); off += (size_t)NUM_GRAPHS * 32 * 4;
    size_t zbytes = (size_t)(ws + off - zbase);
    // ---- sort buffers (fully overwritten each call) ----
    int*   woff = (int*)(ws + off);   off += (size_t)N_NODES * 4;
    int*   bsum = (int*)(ws + off);   off += (size_t)NSCAN_BLK * 4;
    int*   ses  = (int*)(ws + off);   off += (size_t)N_EDGES * 4;
    int*   sed  = (int*)(ws + off);   off += (size_t)N_EDGES * 4;
    float* sea  = (float*)(ws + off); off += (size_t)N_EDGES * 4;

    hipMemsetAsync(zbase, 0, zbytes, stream);

    k0_hist<<<(N_EDGES + 255) / 256, 256, 0, stream>>>(src, dst, deg, cntd);
    k0_scanA<<<NSCAN_BLK, 1024, 0, stream>>>(deg, woff, bsum);
    k0_scanB<<<NSCAN_BLK, 1024, 0, stream>>>(bsum, woff);
    k0_scatter<<<(N_EDGES + 255) / 256, 256, 0, stream>>>(src, dst, ea, woff, ses, sed, sea);
    k1_p1<<<(N_NODES + 15) / 16, 256, 0, stream>>>(x, nn1_w2, nn1_b2, c1_root, P1, R1);
    k2_edge1<<<(N_EDGES + 15) / 16, 256, 0, stream>>>(P1, ses, sed, sea, nn1_w1, nn1_b1, agg1);
    k4_p2<<<(N_NODES + 7) / 8, 256, 0, stream>>>(agg1, cntd, R1, c1_bias, nn2_w2, nn2_b2, c2_root, P2, R2);
    k5_edge2<<<(N_EDGES + 7) / 8, 256, 0, stream>>>(P2, ses, sed, sea, nn2_w1, nn2_b1, agg2);
    k6_partial<<<512, 256, 0, stream>>>(agg2, cntd, R2, c2_bias, batch, gsum);
    k8_head<<<1, 256, 0, stream>>>(gsum, batch, fc1w, fc1b, fc2w, fc2b, (float*)d_out);
}